// Round 1
// baseline (519.873 us; speedup 1.0000x reference)
//
#include <hip/hip_runtime.h>
#include <hip/hip_bf16.h>
#include <hip/hip_fp16.h>

#define S_LEN 4096
#define HD 64
#define NH 8
#define BL 128
#define NB 32
#define DM 512

// ---------------------------------------------------------------------------
// GEMM: C[M,N] = X[M,K] @ W[K,N], M=8192, N=K=512.
// MODE 0: X row-major, C row-major.
// MODE 1: X row-major, C scattered to (B,h,S,hd) layout (projection output).
// MODE 2: X in concatenated (B,h,S,hd) layout with k-index = h*64+d,
//         W rows permuted (wrow = (k&63)*8 + (k>>6)), C row-major.
//         This folds the reference's transpose(0,2,3,1) into addressing.
// Tile: 128x64, BK=16, 256 threads, 8x4 per thread.
// ---------------------------------------------------------------------------
template <int MODE>
__global__ __launch_bounds__(256, 4) void gemm_kernel(
    const float* __restrict__ X, const float* __restrict__ W,
    float* __restrict__ C) {
  __shared__ float Xs[16 * 132];  // [BK][128+4] transposed (k-major)
  __shared__ float Ws[16 * 68];   // [BK][64+4]

  const int tid = threadIdx.x;
  const int bm = blockIdx.x * 128;
  const int bn = blockIdx.y * 64;
  const int tx = tid & 15;   // col group
  const int ty = tid >> 4;   // row group

  const int lxr = tid >> 2;        // 0..63  (X-load row)
  const int lxc = (tid & 3) * 4;   // 0,4,8,12 (X-load col)
  const int lwr = tid >> 4;        // 0..15 (W-load row)
  const int lwc = (tid & 15) * 4;  // W-load col

  float acc[8][4];
#pragma unroll
  for (int ii = 0; ii < 8; ++ii)
#pragma unroll
    for (int jj = 0; jj < 4; ++jj) acc[ii][jj] = 0.f;

  for (int k0 = 0; k0 < DM; k0 += 16) {
    // ---- global loads to registers ----
    const int kidx = k0 + lxc;
    float4 xa, xb, wv;
    if (MODE == 2) {
      const int r0 = bm + lxr;
      const int b0 = r0 >> 12, s0 = r0 & 4095;
      xa = *(const float4*)&X[((b0 * 8 + (kidx >> 6)) * 4096 + s0) * 64 +
                              (kidx & 63)];
      const int r1 = r0 + 64;
      const int b1 = r1 >> 12, s1 = r1 & 4095;
      xb = *(const float4*)&X[((b1 * 8 + (kidx >> 6)) * 4096 + s1) * 64 +
                              (kidx & 63)];
      const int kw = k0 + lwr;
      const int wrow = (kw & 63) * 8 + (kw >> 6);
      wv = *(const float4*)&W[wrow * DM + bn + lwc];
    } else {
      xa = *(const float4*)&X[(bm + lxr) * DM + kidx];
      xb = *(const float4*)&X[(bm + lxr + 64) * DM + kidx];
      wv = *(const float4*)&W[(k0 + lwr) * DM + bn + lwc];
    }

    __syncthreads();  // previous iteration's compute done
    Xs[(lxc + 0) * 132 + lxr] = xa.x;
    Xs[(lxc + 1) * 132 + lxr] = xa.y;
    Xs[(lxc + 2) * 132 + lxr] = xa.z;
    Xs[(lxc + 3) * 132 + lxr] = xa.w;
    Xs[(lxc + 0) * 132 + lxr + 64] = xb.x;
    Xs[(lxc + 1) * 132 + lxr + 64] = xb.y;
    Xs[(lxc + 2) * 132 + lxr + 64] = xb.z;
    Xs[(lxc + 3) * 132 + lxr + 64] = xb.w;
    *(float4*)&Ws[lwr * 68 + lwc] = wv;
    __syncthreads();

#pragma unroll
    for (int kk = 0; kk < 16; ++kk) {
      const float4 a0 = *(const float4*)&Xs[kk * 132 + ty * 8];
      const float4 a1 = *(const float4*)&Xs[kk * 132 + ty * 8 + 4];
      const float4 b4 = *(const float4*)&Ws[kk * 68 + tx * 4];
      const float ar[8] = {a0.x, a0.y, a0.z, a0.w, a1.x, a1.y, a1.z, a1.w};
      const float br[4] = {b4.x, b4.y, b4.z, b4.w};
#pragma unroll
      for (int ii = 0; ii < 8; ++ii)
#pragma unroll
        for (int jj = 0; jj < 4; ++jj)
          acc[ii][jj] = fmaf(ar[ii], br[jj], acc[ii][jj]);
    }
  }

  // ---- write out ----
#pragma unroll
  for (int ii = 0; ii < 8; ++ii) {
    const int r = bm + ty * 8 + ii;
    float4 o;
    o.x = acc[ii][0]; o.y = acc[ii][1]; o.z = acc[ii][2]; o.w = acc[ii][3];
    if (MODE == 1) {
      const int b = r >> 12, s = r & 4095;
      const int hblk = bn >> 6;  // BN=64-aligned -> one head per block col
      *(float4*)&C[((b * 8 + hblk) * 4096 + s) * 64 + tx * 4] = o;
    } else {
      *(float4*)&C[r * DM + bn + tx * 4] = o;
    }
  }
}

// ---------------------------------------------------------------------------
// Local attention: grid (nb=32, h=8, B=2), 128 threads (one per query row).
// Per block: q rows in registers; rel_emb staged -> qrel (fp16, LDS);
// K/V window processed in 12 tiles of 32 keys with online softmax.
// LDS = 67.6 KB -> 2 blocks/CU -> 4 waves/CU (1 per SIMD), grid fully
// resident (512 blocks / 256 CUs).
// ---------------------------------------------------------------------------
__global__ __launch_bounds__(128, 1) void attn_kernel(
    const float* __restrict__ qg, const float* __restrict__ kg_,
    const float* __restrict__ vg, const float* __restrict__ rel,
    float* __restrict__ pre) {
  const int n = blockIdx.x;
  const int hh = blockIdx.y;
  const int b = blockIdx.z;
  const int i = threadIdx.x;  // query row 0..127

  __shared__ float smem[16896];            // 67.6 KB total
  __half* qrelH = (__half*)smem;           // [128][130] halves = 8320 floats
  float* Ks = smem + 8320;                 // [32][68]
  float* Vs = Ks + 2176;                   // [32][68]
  float* es = Vs + 2176;                   // [128][33]
  float* reS = smem + 8320;                // overlay: 129*64 = 8256 <= 8576

  // ---- q row -> registers ----
  const float* qrow = qg + ((b * NH + hh) * S_LEN + n * BL + i) * HD;
  float4 qv[16];
#pragma unroll
  for (int d4 = 0; d4 < 16; ++d4) qv[d4] = *(const float4*)(qrow + d4 * 4);

  // ---- stage rel_emb[h] (129x64 fp32) ----
  const float* rh = rel + hh * (129 * 64);
  for (int idx = i; idx < 129 * 16; idx += 128)
    *(float4*)(reS + idx * 4) = *(const float4*)(rh + idx * 4);
  __syncthreads();

  // ---- qrel[i][r] = dot(q_row, rel[h][r]) ----
  for (int r = 0; r < 129; ++r) {
    float4 a = {0.f, 0.f, 0.f, 0.f};
#pragma unroll
    for (int d4 = 0; d4 < 16; ++d4) {
      const float4 rv = *(const float4*)(reS + r * 64 + d4 * 4);
      a.x = fmaf(rv.x, qv[d4].x, a.x);
      a.y = fmaf(rv.y, qv[d4].y, a.y);
      a.z = fmaf(rv.z, qv[d4].z, a.z);
      a.w = fmaf(rv.w, qv[d4].w, a.w);
    }
    qrelH[i * 130 + r] = __float2half(a.x + a.y + a.z + a.w);
  }
  __syncthreads();  // reS region about to be reused as K/V tiles

  // ---- online softmax over the 384-key window, tiles of 32 ----
  float m = -1e30f, l = 0.f;
  float4 Ov[16];
#pragma unroll
  for (int d4 = 0; d4 < 16; ++d4) Ov[d4] = {0.f, 0.f, 0.f, 0.f};

  const float* kbase = kg_ + (b * NH + hh) * S_LEN * HD;
  const float* vbase = vg + (b * NH + hh) * S_LEN * HD;

  const int t0 = (n == 0) ? 4 : 0;
  const int t1 = (n == NB - 1) ? 8 : 12;

  for (int t = t0; t < t1; ++t) {
    const int j0 = t * 32;
    // ---- cooperative K/V tile load (32 rows x 64) ----
    {
      const int c4 = (i & 15) * 4;
      const int r0 = i >> 4;  // 0..7
#pragma unroll
      for (int rr = 0; rr < 4; ++rr) {
        const int r = r0 + rr * 8;
        const int kgl = n * BL - BL + j0 + r;
        float4 kv = {0.f, 0.f, 0.f, 0.f}, vv = {0.f, 0.f, 0.f, 0.f};
        if ((unsigned)kgl < S_LEN) {
          kv = *(const float4*)(kbase + kgl * HD + c4);
          vv = *(const float4*)(vbase + kgl * HD + c4);
        }
        *(float4*)(Ks + r * 68 + c4) = kv;
        *(float4*)(Vs + r * 68 + c4) = vv;
      }
    }
    __syncthreads();

    // ---- energy for 32 keys ----
    float tmax = -1e30f;
    for (int jj = 0; jj < 32; ++jj) {
      float4 a = {0.f, 0.f, 0.f, 0.f};
#pragma unroll
      for (int d4 = 0; d4 < 16; ++d4) {
        const float4 k4 = *(const float4*)(Ks + jj * 68 + d4 * 4);
        a.x = fmaf(k4.x, qv[d4].x, a.x);
        a.y = fmaf(k4.y, qv[d4].y, a.y);
        a.z = fmaf(k4.z, qv[d4].z, a.z);
        a.w = fmaf(k4.w, qv[d4].w, a.w);
      }
      const int j = j0 + jj;
      const int dpos = j - BL - i;
      const int idc = dpos < -64 ? 0 : (dpos > 64 ? 128 : dpos + 64);
      float val =
          (a.x + a.y + a.z + a.w + __half2float(qrelH[i * 130 + idc])) * 0.125f;
      const int kgl = n * BL - BL + j;
      const bool bad = (dpos > 127) || (dpos < -127) || ((unsigned)kgl >= S_LEN);
      val = bad ? -1e30f : val;
      tmax = fmaxf(tmax, val);
      es[i * 33 + jj] = val;
    }

    // ---- online rescale ----
    const float newm = fmaxf(m, tmax);
    const float sc = __expf(m - newm);
    l *= sc;
#pragma unroll
    for (int d4 = 0; d4 < 16; ++d4) {
      Ov[d4].x *= sc; Ov[d4].y *= sc; Ov[d4].z *= sc; Ov[d4].w *= sc;
    }
    m = newm;

    // ---- probabilities + PV ----
    for (int jj = 0; jj < 32; ++jj) {
      const float p = __expf(es[i * 33 + jj] - m);
      l += p;
#pragma unroll
      for (int d4 = 0; d4 < 16; ++d4) {
        const float4 v4 = *(const float4*)(Vs + jj * 68 + d4 * 4);
        Ov[d4].x = fmaf(p, v4.x, Ov[d4].x);
        Ov[d4].y = fmaf(p, v4.y, Ov[d4].y);
        Ov[d4].z = fmaf(p, v4.z, Ov[d4].z);
        Ov[d4].w = fmaf(p, v4.w, Ov[d4].w);
      }
    }
    __syncthreads();  // before next tile overwrites Ks/Vs
  }

  // ---- epilogue: normalize, write (B,h,S,hd)-concat layout ----
  const float inv = 1.f / l;
  float* prow = pre + ((b * NH + hh) * S_LEN + n * BL + i) * HD;
#pragma unroll
  for (int d4 = 0; d4 < 16; ++d4) {
    float4 o = Ov[d4];
    o.x *= inv; o.y *= inv; o.z *= inv; o.w *= inv;
    *(float4*)(prow + d4 * 4) = o;
  }
}

// ---------------------------------------------------------------------------
extern "C" void kernel_launch(void* const* d_in, const int* in_sizes, int n_in,
                              void* d_out, int out_size, void* d_ws,
                              size_t ws_size, hipStream_t stream) {
  const float* Q = (const float*)d_in[0];
  const float* K = (const float*)d_in[1];
  const float* V = (const float*)d_in[2];
  // d_in[3] segment_ids: all zeros, unused by reference math
  const float* Wq = (const float*)d_in[4];
  const float* Wk = (const float*)d_in[5];
  const float* Wv = (const float*)d_in[6];
  const float* Wo = (const float*)d_in[7];
  const float* rel = (const float*)d_in[8];
  float* out = (float*)d_out;

  float* ws = (float*)d_ws;
  const int NELEM = 2 * NH * S_LEN * HD;  // 4,194,304
  float* qb = ws;
  float* kb = qb + NELEM;
  float* vb = kb + NELEM;
  float* pre = vb + NELEM;

  dim3 gg(64, 8), bb(256);
  gemm_kernel<1><<<gg, bb, 0, stream>>>(Q, Wq, qb);
  gemm_kernel<1><<<gg, bb, 0, stream>>>(K, Wk, kb);
  gemm_kernel<1><<<gg, bb, 0, stream>>>(V, Wv, vb);
  attn_kernel<<<dim3(NB, NH, 2), dim3(128), 0, stream>>>(qb, kb, vb, rel, pre);
  gemm_kernel<2><<<gg, bb, 0, stream>>>(pre, Wo, out);
}

// Round 2
// 446.637 us; speedup vs baseline: 1.1640x; 1.1640x over previous
//
#include <hip/hip_runtime.h>
#include <hip/hip_bf16.h>
#include <hip/hip_fp16.h>

typedef unsigned short u16;
typedef __bf16 bf16_t;
typedef bf16_t bf16x8 __attribute__((ext_vector_type(8)));
typedef float f32x4 __attribute__((ext_vector_type(4)));
typedef u16 u16x4 __attribute__((ext_vector_type(4)));
typedef u16 u16x8 __attribute__((ext_vector_type(8)));

#define S_LEN 4096
#define NH 8
#define HD 64
#define DM 512
#define NB 32

__device__ __forceinline__ u16 f2bf(float f) {
  unsigned int u = __builtin_bit_cast(unsigned int, f);
  u = (u + 0x7fff + ((u >> 16) & 1)) >> 16;  // RNE
  return (u16)u;
}
__device__ __forceinline__ float bf2f(u16 h) {
  unsigned int u = ((unsigned int)h) << 16;
  return __builtin_bit_cast(float, u);
}

#define GLDS16(gaddr, laddr)                                                  \
  __builtin_amdgcn_global_load_lds(                                           \
      (const __attribute__((address_space(1))) unsigned int*)(gaddr),         \
      (__attribute__((address_space(3))) unsigned int*)(laddr), 16, 0, 0)

// ---------------------------------------------------------------------------
// fp32 -> bf16 flat convert for Q,K,V (z selects tensor). grid (4096,3)x256.
// ---------------------------------------------------------------------------
__global__ __launch_bounds__(256) void conv_big(
    const float* __restrict__ Q, const float* __restrict__ K,
    const float* __restrict__ V, u16* __restrict__ Qb, u16* __restrict__ Kb,
    u16* __restrict__ Vb) {
  const int z = blockIdx.y;
  const float* src = z == 0 ? Q : (z == 1 ? K : V);
  u16* dst = z == 0 ? Qb : (z == 1 ? Kb : Vb);
  const size_t idx = ((size_t)blockIdx.x * 256 + threadIdx.x) * 4;
  const float4 v = *(const float4*)(src + idx);
  u16x4 o;
  o[0] = f2bf(v.x); o[1] = f2bf(v.y); o[2] = f2bf(v.z); o[3] = f2bf(v.w);
  *(u16x4*)(dst + idx) = o;
}

// ---------------------------------------------------------------------------
// Weights: fp32 [K][N] -> bf16 transposed [N][K]; Wo additionally row-permuted
// (wrow = (k&63)*8 + (k>>6)) to fold the reference transpose(0,2,3,1).
// grid (256,4)x256.
// ---------------------------------------------------------------------------
__global__ __launch_bounds__(256) void conv_w(
    const float* __restrict__ Wq, const float* __restrict__ Wk,
    const float* __restrict__ Wv, const float* __restrict__ Wo,
    u16* __restrict__ WqT, u16* __restrict__ WkT, u16* __restrict__ WvT,
    u16* __restrict__ WoT) {
  const int z = blockIdx.y;
  const float* src = z == 0 ? Wq : (z == 1 ? Wk : (z == 2 ? Wv : Wo));
  u16* dst = z == 0 ? WqT : (z == 1 ? WkT : (z == 2 ? WvT : WoT));
  const int idx4 = blockIdx.x * 256 + threadIdx.x;  // 0..65535
  const int nrow = idx4 >> 7;
  const int kbase = (idx4 & 127) * 4;
  u16x4 o;
#pragma unroll
  for (int j = 0; j < 4; ++j) {
    const int k = kbase + j;
    const int srow = (z == 3) ? ((k & 63) * 8 + (k >> 6)) : k;
    o[j] = f2bf(src[srow * DM + nrow]);
  }
  *(u16x4*)(dst + nrow * DM + kbase) = o;
}

// ---------------------------------------------------------------------------
// bf16 MFMA GEMM, 128x128 tile, BK=32, 4 waves (each 64x64), B given as N x K.
// MODE 1: A row-major [8192][512]; C scattered bf16 to (b,h,s,d); z picks QKV.
// MODE 2: A = pre in (b,h,s,d) with k = h*64+d addressing; C fp32 row-major.
// ---------------------------------------------------------------------------
template <int MODE>
__global__ __launch_bounds__(256, 2) void gemm_bf16(
    const u16* __restrict__ A0, const u16* __restrict__ A1,
    const u16* __restrict__ A2, const u16* __restrict__ B0,
    const u16* __restrict__ B1, const u16* __restrict__ B2,
    u16* __restrict__ C0, u16* __restrict__ C1, u16* __restrict__ C2,
    float* __restrict__ Cf) {
  __shared__ u16 As[128 * 32];
  __shared__ u16 Bs[128 * 32];

  const int z = blockIdx.z;
  const u16* A = (MODE == 1) ? (z == 0 ? A0 : (z == 1 ? A1 : A2)) : A0;
  const u16* Bt = (MODE == 1) ? (z == 0 ? B0 : (z == 1 ? B1 : B2)) : B0;
  u16* Cb = (MODE == 1) ? (z == 0 ? C0 : (z == 1 ? C1 : C2)) : (u16*)0;

  const int tid = threadIdx.x;
  const int lane = tid & 63;
  const int w = tid >> 6;
  const int bm = blockIdx.x * 128;
  const int bn = blockIdx.y * 128;

  const int srow = lane >> 2;       // 0..15 within chunk
  const int scol = (lane & 3) * 8;  // k offset 0,8,16,24

  f32x4 acc[4][4];
#pragma unroll
  for (int m = 0; m < 4; ++m)
#pragma unroll
    for (int nf = 0; nf < 4; ++nf) acc[m][nf] = f32x4{0.f, 0.f, 0.f, 0.f};

  const int wr = w >> 1, wc = w & 1;
  const int lrow = lane & 15;
  const int lk = (lane >> 4) * 8;

  for (int k0 = 0; k0 < DM; k0 += 32) {
#pragma unroll
    for (int t = 0; t < 2; ++t) {
      const int c = t * 4 + w;       // chunk 0..7 -> rows [c*16, c*16+16)
      const int ar = c * 16 + srow;  // tile row
      long gidx;
      if (MODE == 2) {
        const int r = bm + ar;
        const int b = r >> 12, s = r & 4095;
        const int k = k0 + scol;
        gidx = ((long)((b * 8 + (k >> 6)) * 4096 + s)) * 64 + (k & 63);
      } else {
        gidx = (long)(bm + ar) * DM + k0 + scol;
      }
      GLDS16(A + gidx, &As[c * 512]);
      const long bidx = (long)(bn + ar) * DM + k0 + scol;
      GLDS16(Bt + bidx, &Bs[c * 512]);
    }
    __syncthreads();

    bf16x8 af[4], bfr[4];
#pragma unroll
    for (int m = 0; m < 4; ++m)
      af[m] = *(const bf16x8*)&As[(wr * 64 + m * 16 + lrow) * 32 + lk];
#pragma unroll
    for (int nf = 0; nf < 4; ++nf)
      bfr[nf] = *(const bf16x8*)&Bs[(wc * 64 + nf * 16 + lrow) * 32 + lk];
#pragma unroll
    for (int m = 0; m < 4; ++m)
#pragma unroll
      for (int nf = 0; nf < 4; ++nf)
        acc[m][nf] = __builtin_amdgcn_mfma_f32_16x16x32_bf16(
            af[m], bfr[nf], acc[m][nf], 0, 0, 0);
    __syncthreads();
  }

  // epilogue: C/D layout col=lane&15, row=(lane>>4)*4+reg
  const int lr4 = (lane >> 4) * 4;
  const int lc = lane & 15;
#pragma unroll
  for (int m = 0; m < 4; ++m) {
#pragma unroll
    for (int nf = 0; nf < 4; ++nf) {
#pragma unroll
      for (int j = 0; j < 4; ++j) {
        const int r = bm + wr * 64 + m * 16 + lr4 + j;
        const int cg = bn + wc * 64 + nf * 16 + lc;
        const float val = acc[m][nf][j];
        if (MODE == 1) {
          const int b = r >> 12, s = r & 4095;
          Cb[((long)((b * 8 + (cg >> 6)) * 4096 + s)) * 64 + (cg & 63)] =
              f2bf(val);
        } else {
          Cf[(long)r * DM + cg] = val;
        }
      }
    }
  }
}

// ---------------------------------------------------------------------------
// Local attention (fp32 math, bf16 I/O). grid (32,8,2) x 128 threads.
// Thread = one query row. LDS: qrel fp16 [128][130] + K/V fp32 tiles [32][68].
// 50.7 KB -> 3 blocks/CU (6 waves). es kept in registers; rel read from L2.
// ---------------------------------------------------------------------------
__global__ __launch_bounds__(128) void attn_kernel(
    const u16* __restrict__ qg, const u16* __restrict__ kg_,
    const u16* __restrict__ vg, const float* __restrict__ rel,
    u16* __restrict__ pre) {
  const int n = blockIdx.x;
  const int hh = blockIdx.y;
  const int b = blockIdx.z;
  const int i = threadIdx.x;

  __shared__ __align__(16) unsigned char smem[50688];
  __half* qrelH = (__half*)smem;       // [128][130]
  float* Ks = (float*)(smem + 33280);  // [32][68]
  float* Vs = Ks + 2176;               // [32][68]

  // ---- q row -> fp32 registers ----
  const u16* qrow = qg + (size_t)((b * NH + hh) * S_LEN + n * 128 + i) * HD;
  float4 qv[16];
#pragma unroll
  for (int d8 = 0; d8 < 8; ++d8) {
    const u16x8 t = *(const u16x8*)(qrow + d8 * 8);
    float4 a, c;
    a.x = bf2f(t[0]); a.y = bf2f(t[1]); a.z = bf2f(t[2]); a.w = bf2f(t[3]);
    c.x = bf2f(t[4]); c.y = bf2f(t[5]); c.z = bf2f(t[6]); c.w = bf2f(t[7]);
    qv[2 * d8] = a; qv[2 * d8 + 1] = c;
  }

  // ---- qrel[i][r] = q . rel[h][r] (rel read uniform -> scalar/L2) ----
  const float* rh = rel + (size_t)hh * (129 * 64);
  for (int r = 0; r < 129; ++r) {
    float4 a = {0.f, 0.f, 0.f, 0.f};
#pragma unroll
    for (int d4 = 0; d4 < 16; ++d4) {
      const float4 rv = *(const float4*)(rh + r * 64 + d4 * 4);
      a.x = fmaf(rv.x, qv[d4].x, a.x);
      a.y = fmaf(rv.y, qv[d4].y, a.y);
      a.z = fmaf(rv.z, qv[d4].z, a.z);
      a.w = fmaf(rv.w, qv[d4].w, a.w);
    }
    qrelH[i * 130 + r] = __float2half(a.x + a.y + a.z + a.w);
  }
  // no barrier needed: qrelH row i is thread-private

  float m = -1e30f, l = 0.f;
  float4 Ov[16];
#pragma unroll
  for (int d4 = 0; d4 < 16; ++d4) Ov[d4] = {0.f, 0.f, 0.f, 0.f};

  const u16* kbase = kg_ + (size_t)((b * NH + hh) * S_LEN) * HD;
  const u16* vbase = vg + (size_t)((b * NH + hh) * S_LEN) * HD;

  const int t0 = (n == 0) ? 4 : 0;
  const int t1 = (n == NB - 1) ? 8 : 12;

  for (int t = t0; t < t1; ++t) {
    const int j0 = t * 32;
    // ---- cooperative K/V tile load (bf16 -> fp32 LDS) ----
    {
      const int c4 = (i & 15) * 4;
      const int r0 = i >> 4;
#pragma unroll
      for (int rr = 0; rr < 4; ++rr) {
        const int r = r0 + rr * 8;
        const int kgl = n * 128 - 128 + j0 + r;
        float4 kv = {0.f, 0.f, 0.f, 0.f}, vv = {0.f, 0.f, 0.f, 0.f};
        if ((unsigned)kgl < (unsigned)S_LEN) {
          const u16x4 ku = *(const u16x4*)(kbase + (size_t)kgl * HD + c4);
          const u16x4 vu = *(const u16x4*)(vbase + (size_t)kgl * HD + c4);
          kv.x = bf2f(ku[0]); kv.y = bf2f(ku[1]);
          kv.z = bf2f(ku[2]); kv.w = bf2f(ku[3]);
          vv.x = bf2f(vu[0]); vv.y = bf2f(vu[1]);
          vv.z = bf2f(vu[2]); vv.w = bf2f(vu[3]);
        }
        *(float4*)(Ks + r * 68 + c4) = kv;
        *(float4*)(Vs + r * 68 + c4) = vv;
      }
    }
    __syncthreads();

    // ---- energies (registers) ----
    float es_r[32];
    float tmax = -1e30f;
#pragma unroll
    for (int jj = 0; jj < 32; ++jj) {
      float4 a = {0.f, 0.f, 0.f, 0.f};
#pragma unroll
      for (int d4 = 0; d4 < 16; ++d4) {
        const float4 k4 = *(const float4*)(Ks + jj * 68 + d4 * 4);
        a.x = fmaf(k4.x, qv[d4].x, a.x);
        a.y = fmaf(k4.y, qv[d4].y, a.y);
        a.z = fmaf(k4.z, qv[d4].z, a.z);
        a.w = fmaf(k4.w, qv[d4].w, a.w);
      }
      const int j = j0 + jj;
      const int dpos = j - 128 - i;
      const int idc = dpos < -64 ? 0 : (dpos > 64 ? 128 : dpos + 64);
      float val =
          (a.x + a.y + a.z + a.w + __half2float(qrelH[i * 130 + idc])) * 0.125f;
      const int kgl = n * 128 - 128 + j;
      const bool bad =
          (dpos > 127) || (dpos < -127) || ((unsigned)kgl >= (unsigned)S_LEN);
      val = bad ? -1e30f : val;
      tmax = fmaxf(tmax, val);
      es_r[jj] = val;
    }

    // ---- online rescale ----
    const float newm = fmaxf(m, tmax);
    const float sc = __expf(m - newm);
    l *= sc;
#pragma unroll
    for (int d4 = 0; d4 < 16; ++d4) {
      Ov[d4].x *= sc; Ov[d4].y *= sc; Ov[d4].z *= sc; Ov[d4].w *= sc;
    }
    m = newm;

    // ---- probabilities + PV ----
#pragma unroll
    for (int jj = 0; jj < 32; ++jj) {
      const float p = __expf(es_r[jj] - m);
      l += p;
#pragma unroll
      for (int d4 = 0; d4 < 16; ++d4) {
        const float4 v4 = *(const float4*)(Vs + jj * 68 + d4 * 4);
        Ov[d4].x = fmaf(p, v4.x, Ov[d4].x);
        Ov[d4].y = fmaf(p, v4.y, Ov[d4].y);
        Ov[d4].z = fmaf(p, v4.z, Ov[d4].z);
        Ov[d4].w = fmaf(p, v4.w, Ov[d4].w);
      }
    }
    __syncthreads();
  }

  // ---- epilogue: normalize, write bf16 (b,h,s,d) ----
  const float inv = 1.f / l;
  u16* prow = pre + (size_t)((b * NH + hh) * S_LEN + n * 128 + i) * HD;
#pragma unroll
  for (int d8 = 0; d8 < 8; ++d8) {
    u16x8 o;
    const float4 a = Ov[2 * d8], c = Ov[2 * d8 + 1];
    o[0] = f2bf(a.x * inv); o[1] = f2bf(a.y * inv);
    o[2] = f2bf(a.z * inv); o[3] = f2bf(a.w * inv);
    o[4] = f2bf(c.x * inv); o[5] = f2bf(c.y * inv);
    o[6] = f2bf(c.z * inv); o[7] = f2bf(c.w * inv);
    *(u16x8*)(prow + d8 * 8) = o;
  }
}

// ---------------------------------------------------------------------------
extern "C" void kernel_launch(void* const* d_in, const int* in_sizes, int n_in,
                              void* d_out, int out_size, void* d_ws,
                              size_t ws_size, hipStream_t stream) {
  const float* Q = (const float*)d_in[0];
  const float* K = (const float*)d_in[1];
  const float* V = (const float*)d_in[2];
  const float* Wq = (const float*)d_in[4];
  const float* Wk = (const float*)d_in[5];
  const float* Wv = (const float*)d_in[6];
  const float* Wo = (const float*)d_in[7];
  const float* rel = (const float*)d_in[8];
  float* out = (float*)d_out;

  const size_t NE = 4194304;  // 2*8*4096*64
  u16* ws16 = (u16*)d_ws;
  u16* Qb = ws16;
  u16* Kb = Qb + NE;
  u16* Vb = Kb + NE;
  u16* qb = Vb + NE;
  u16* kb = qb + NE;
  u16* vb = kb + NE;
  u16* WqT = vb + NE;
  u16* WkT = WqT + 262144;
  u16* WvT = WkT + 262144;
  u16* WoT = WvT + 262144;
  u16* pre = Qb;  // Qb dead after proj GEMM

  conv_big<<<dim3(4096, 3), 256, 0, stream>>>(Q, K, V, Qb, Kb, Vb);
  conv_w<<<dim3(256, 4), 256, 0, stream>>>(Wq, Wk, Wv, Wo, WqT, WkT, WvT, WoT);
  gemm_bf16<1><<<dim3(64, 4, 3), 256, 0, stream>>>(Qb, Kb, Vb, WqT, WkT, WvT,
                                                   qb, kb, vb, nullptr);
  attn_kernel<<<dim3(NB, NH, 2), 128, 0, stream>>>(qb, kb, vb, rel, pre);
  gemm_bf16<2><<<dim3(64, 4, 1), 256, 0, stream>>>(
      pre, nullptr, nullptr, WoT, nullptr, nullptr, nullptr, nullptr, nullptr,
      out);
}

// Round 3
// 189.129 us; speedup vs baseline: 2.7488x; 2.3615x over previous
//
#include <hip/hip_runtime.h>
#include <hip/hip_bf16.h>

typedef unsigned short u16;
typedef __bf16 bf16_t;
typedef bf16_t bf16x8 __attribute__((ext_vector_type(8)));
typedef float f32x4 __attribute__((ext_vector_type(4)));
typedef u16 u16x4 __attribute__((ext_vector_type(4)));
typedef u16 u16x8 __attribute__((ext_vector_type(8)));

#define S_LEN 4096
#define NH 8
#define HD 64
#define DM 512
#define NB 32

__device__ __forceinline__ u16 f2bf(float f) {
  unsigned int u = __builtin_bit_cast(unsigned int, f);
  u = (u + 0x7fff + ((u >> 16) & 1)) >> 16;  // RNE
  return (u16)u;
}
__device__ __forceinline__ float bf2f(u16 h) {
  unsigned int u = ((unsigned int)h) << 16;
  return __builtin_bit_cast(float, u);
}

#define GLDS16(gaddr, laddr)                                                  \
  __builtin_amdgcn_global_load_lds(                                           \
      (const __attribute__((address_space(1))) unsigned int*)(gaddr),         \
      (__attribute__((address_space(3))) unsigned int*)(laddr), 16, 0, 0)

// ---------------------------------------------------------------------------
// fp32 -> bf16 flat convert for Q,K,V. grid (4096,3) x 256.
// ---------------------------------------------------------------------------
__global__ __launch_bounds__(256) void conv_big(
    const float* __restrict__ Q, const float* __restrict__ K,
    const float* __restrict__ V, u16* __restrict__ Qb, u16* __restrict__ Kb,
    u16* __restrict__ Vb) {
  const int z = blockIdx.y;
  const float* src = z == 0 ? Q : (z == 1 ? K : V);
  u16* dst = z == 0 ? Qb : (z == 1 ? Kb : Vb);
  const size_t idx = ((size_t)blockIdx.x * 256 + threadIdx.x) * 4;
  const float4 v = *(const float4*)(src + idx);
  u16x4 o;
  o[0] = f2bf(v.x); o[1] = f2bf(v.y); o[2] = f2bf(v.z); o[3] = f2bf(v.w);
  *(u16x4*)(dst + idx) = o;
}

// ---------------------------------------------------------------------------
// Weights: fp32 [K][N] -> bf16 transposed [N][K]; Wq scaled by 1/8 (folds the
// 1/sqrt(hd) into q so energy AND rel-bias are both scaled); Wo row-permuted
// (wrow = (k&63)*8 + (k>>6)) to fold transpose(0,2,3,1). grid (256,4) x 256.
// ---------------------------------------------------------------------------
__global__ __launch_bounds__(256) void conv_w(
    const float* __restrict__ Wq, const float* __restrict__ Wk,
    const float* __restrict__ Wv, const float* __restrict__ Wo,
    u16* __restrict__ WqT, u16* __restrict__ WkT, u16* __restrict__ WvT,
    u16* __restrict__ WoT) {
  const int z = blockIdx.y;
  const float* src = z == 0 ? Wq : (z == 1 ? Wk : (z == 2 ? Wv : Wo));
  u16* dst = z == 0 ? WqT : (z == 1 ? WkT : (z == 2 ? WvT : WoT));
  const float scl = (z == 0) ? 0.125f : 1.f;
  const int idx4 = blockIdx.x * 256 + threadIdx.x;
  const int nrow = idx4 >> 7;
  const int kbase = (idx4 & 127) * 4;
  u16x4 o;
#pragma unroll
  for (int j = 0; j < 4; ++j) {
    const int k = kbase + j;
    const int srow = (z == 3) ? ((k & 63) * 8 + (k >> 6)) : k;
    o[j] = f2bf(src[srow * DM + nrow] * scl);
  }
  *(u16x4*)(dst + nrow * DM + kbase) = o;
}

// ---------------------------------------------------------------------------
// rel_emb fp32 [8][129][64] -> bf16 [8][144][64] (row-padded; pad rows stay
// poison and are never read: idc <= 128). grid 129 x 128.
// ---------------------------------------------------------------------------
__global__ __launch_bounds__(128) void conv_rel(const float* __restrict__ rel,
                                                u16* __restrict__ relb) {
  const int e = (blockIdx.x * 128 + threadIdx.x) * 4;  // 66048 floats total
  const int h = e / (129 * 64);
  const int rem = e - h * (129 * 64);
  const float4 v = *(const float4*)(rel + e);
  u16x4 o;
  o[0] = f2bf(v.x); o[1] = f2bf(v.y); o[2] = f2bf(v.z); o[3] = f2bf(v.w);
  *(u16x4*)(relb + (size_t)h * (144 * 64) + rem) = o;
}

// ---------------------------------------------------------------------------
// bf16 MFMA GEMM, 128x128 tile, BK=32, 4 waves, B given as N x K.
// MODE 1: A row-major; C scattered bf16 to (b,h,s,d); z picks Q/K/V.
// MODE 2: A = attn-out in (b,h,s,d), k = h*64+d addressing; C fp32 row-major.
// ---------------------------------------------------------------------------
template <int MODE>
__global__ __launch_bounds__(256, 2) void gemm_bf16(
    const u16* __restrict__ A0, const u16* __restrict__ A1,
    const u16* __restrict__ A2, const u16* __restrict__ B0,
    const u16* __restrict__ B1, const u16* __restrict__ B2,
    u16* __restrict__ C0, u16* __restrict__ C1, u16* __restrict__ C2,
    float* __restrict__ Cf) {
  __shared__ u16 As[128 * 32];
  __shared__ u16 Bs[128 * 32];

  const int z = blockIdx.z;
  const u16* A = (MODE == 1) ? (z == 0 ? A0 : (z == 1 ? A1 : A2)) : A0;
  const u16* Bt = (MODE == 1) ? (z == 0 ? B0 : (z == 1 ? B1 : B2)) : B0;
  u16* Cb = (MODE == 1) ? (z == 0 ? C0 : (z == 1 ? C1 : C2)) : (u16*)0;

  const int tid = threadIdx.x;
  const int lane = tid & 63;
  const int w = tid >> 6;
  const int bm = blockIdx.x * 128;
  const int bn = blockIdx.y * 128;

  const int srow = lane >> 2;
  const int scol = (lane & 3) * 8;

  f32x4 acc[4][4];
#pragma unroll
  for (int m = 0; m < 4; ++m)
#pragma unroll
    for (int nf = 0; nf < 4; ++nf) acc[m][nf] = f32x4{0.f, 0.f, 0.f, 0.f};

  const int wr = w >> 1, wc = w & 1;
  const int lrow = lane & 15;
  const int lk = (lane >> 4) * 8;

  for (int k0 = 0; k0 < DM; k0 += 32) {
#pragma unroll
    for (int t = 0; t < 2; ++t) {
      const int c = t * 4 + w;
      const int ar = c * 16 + srow;
      long gidx;
      if (MODE == 2) {
        const int r = bm + ar;
        const int b = r >> 12, s = r & 4095;
        const int k = k0 + scol;
        gidx = ((long)((b * 8 + (k >> 6)) * 4096 + s)) * 64 + (k & 63);
      } else {
        gidx = (long)(bm + ar) * DM + k0 + scol;
      }
      GLDS16(A + gidx, &As[c * 512]);
      const long bidx = (long)(bn + ar) * DM + k0 + scol;
      GLDS16(Bt + bidx, &Bs[c * 512]);
    }
    __syncthreads();

    bf16x8 af[4], bfr[4];
#pragma unroll
    for (int m = 0; m < 4; ++m)
      af[m] = *(const bf16x8*)&As[(wr * 64 + m * 16 + lrow) * 32 + lk];
#pragma unroll
    for (int nf = 0; nf < 4; ++nf)
      bfr[nf] = *(const bf16x8*)&Bs[(wc * 64 + nf * 16 + lrow) * 32 + lk];
#pragma unroll
    for (int m = 0; m < 4; ++m)
#pragma unroll
      for (int nf = 0; nf < 4; ++nf)
        acc[m][nf] = __builtin_amdgcn_mfma_f32_16x16x32_bf16(
            af[m], bfr[nf], acc[m][nf], 0, 0, 0);
    __syncthreads();
  }

  const int lr4 = (lane >> 4) * 4;
  const int lc = lane & 15;
#pragma unroll
  for (int m = 0; m < 4; ++m) {
#pragma unroll
    for (int nf = 0; nf < 4; ++nf) {
#pragma unroll
      for (int j = 0; j < 4; ++j) {
        const int r = bm + wr * 64 + m * 16 + lr4 + j;
        const int cg = bn + wc * 64 + nf * 16 + lc;
        const float val = acc[m][nf][j];
        if (MODE == 1) {
          const int b = r >> 12, s = r & 4095;
          Cb[((long)((b * 8 + (cg >> 6)) * 4096 + s)) * 64 + (cg & 63)] =
              f2bf(val);
        } else {
          Cf[(long)r * DM + cg] = val;
        }
      }
    }
  }
}

// ---------------------------------------------------------------------------
// MFMA local attention. grid (32,8,2) x 256 (4 waves, 32 q each).
// Per kv-tile (64 keys): QK^T 16 MFMA, bias gather from LDS qrel table,
// wave-parallel online softmax (shfl_xor in 16-lane groups), P via per-wave
// LDS, PV 16 MFMA. K row-major [64][72]; V transposed [64d][72k] so both
// MFMA B-operands are contiguous ds_read_b128. LDS 70.7KB -> 2 blocks/CU.
// ---------------------------------------------------------------------------
__global__ __launch_bounds__(256, 2) void attn_mfma(
    const u16* __restrict__ qg, const u16* __restrict__ kgl,
    const u16* __restrict__ vgl, const u16* __restrict__ relb,
    u16* __restrict__ pre) {
  const int n = blockIdx.x, hh = blockIdx.y, b = blockIdx.z;
  const int tid = threadIdx.x;
  const int lane = tid & 63, w = tid >> 6;
  const int g = lane >> 4, lc = lane & 15;

  __shared__ u16 Ks[64 * 72];
  __shared__ u16 Vt[64 * 72];
  __shared__ u16 Pl[4][32 * 72];
  __shared__ u16 qrelL[128 * 132];

  const size_t bh = (size_t)(b * NH + hh);

  // ---- Q fragments: A[row=q][k=d], row = lc+16qt, d = g*8+32dc ----
  const u16* qbase = qg + (bh * S_LEN + (size_t)n * 128 + w * 32) * HD;
  bf16x8 qf[2][2];
#pragma unroll
  for (int qt = 0; qt < 2; ++qt)
#pragma unroll
    for (int dc = 0; dc < 2; ++dc)
      qf[qt][dc] =
          *(const bf16x8*)(qbase + (lc + 16 * qt) * HD + g * 8 + 32 * dc);

  // ---- qrel table via MFMA: qrelL[q][r] = q . rel[r] ----
  const u16* rh = relb + (size_t)hh * (144 * 64);
#pragma unroll
  for (int rt = 0; rt < 9; ++rt) {
    f32x4 acc[2] = {{0.f, 0.f, 0.f, 0.f}, {0.f, 0.f, 0.f, 0.f}};
#pragma unroll
    for (int dc = 0; dc < 2; ++dc) {
      const bf16x8 rf =
          *(const bf16x8*)(rh + (lc + 16 * rt) * 64 + g * 8 + 32 * dc);
#pragma unroll
      for (int qt = 0; qt < 2; ++qt)
        acc[qt] = __builtin_amdgcn_mfma_f32_16x16x32_bf16(qf[qt][dc], rf,
                                                          acc[qt], 0, 0, 0);
    }
#pragma unroll
    for (int qt = 0; qt < 2; ++qt)
#pragma unroll
      for (int jj = 0; jj < 4; ++jj)
        qrelL[(w * 32 + qt * 16 + g * 4 + jj) * 132 + lc + 16 * rt] =
            f2bf(acc[qt][jj]);
  }

  float m_r[2][4], l_r[2][4];
  f32x4 Oa[2][4];
#pragma unroll
  for (int qt = 0; qt < 2; ++qt)
#pragma unroll
    for (int jj = 0; jj < 4; ++jj) {
      m_r[qt][jj] = -1e30f;
      l_r[qt][jj] = 0.f;
    }
#pragma unroll
  for (int qt = 0; qt < 2; ++qt)
#pragma unroll
    for (int dt = 0; dt < 4; ++dt) Oa[qt][dt] = f32x4{0.f, 0.f, 0.f, 0.f};

  const u16* kbase = kgl + bh * S_LEN * HD;
  const u16* vbase = vgl + bh * S_LEN * HD;
  const int sk = tid & 63;
  const int sd = (tid >> 6) * 16;

  const int t0 = (n == 0) ? 2 : 0;
  const int t1 = (n == NB - 1) ? 4 : 6;

  for (int t = t0; t < t1; ++t) {
    // ---- stage K row-major + V transposed (clamped rows; masked later) ----
    {
      const int kglob = n * 128 - 128 + t * 64 + sk;
      const int kc = min(max(kglob, 0), S_LEN - 1);
      const u16* krow = kbase + (size_t)kc * HD + sd;
      const u16* vrow = vbase + (size_t)kc * HD + sd;
      const u16x8 ka = *(const u16x8*)krow;
      const u16x8 kb2 = *(const u16x8*)(krow + 8);
      const u16x8 va = *(const u16x8*)vrow;
      const u16x8 vb2 = *(const u16x8*)(vrow + 8);
      *(u16x8*)&Ks[sk * 72 + sd] = ka;
      *(u16x8*)&Ks[sk * 72 + sd + 8] = kb2;
#pragma unroll
      for (int e = 0; e < 8; ++e) {
        Vt[(sd + e) * 72 + sk] = va[e];
        Vt[(sd + 8 + e) * 72 + sk] = vb2[e];
      }
    }
    __syncthreads();

    // ---- QK^T: E[q][k] ----
    f32x4 E[2][4];
#pragma unroll
    for (int qt = 0; qt < 2; ++qt)
#pragma unroll
      for (int kt = 0; kt < 4; ++kt) E[qt][kt] = f32x4{0.f, 0.f, 0.f, 0.f};
#pragma unroll
    for (int kt = 0; kt < 4; ++kt)
#pragma unroll
      for (int dc = 0; dc < 2; ++dc) {
        const bf16x8 kf =
            *(const bf16x8*)&Ks[(lc + 16 * kt) * 72 + g * 8 + 32 * dc];
#pragma unroll
        for (int qt = 0; qt < 2; ++qt)
          E[qt][kt] = __builtin_amdgcn_mfma_f32_16x16x32_bf16(qf[qt][dc], kf,
                                                              E[qt][kt], 0, 0, 0);
      }

    // ---- bias + mask (lane holds col k = lc+16kt, row q = g*4+jj+16qt) ----
#pragma unroll
    for (int qt = 0; qt < 2; ++qt)
#pragma unroll
      for (int jj = 0; jj < 4; ++jj) {
        const int q = w * 32 + qt * 16 + g * 4 + jj;
#pragma unroll
        for (int kt = 0; kt < 4; ++kt) {
          const int j = t * 64 + kt * 16 + lc;
          const int dpos = j - 128 - q;
          const int kglob = n * 128 - 128 + j;
          const int idc = min(max(dpos, -64), 64) + 64;
          const float bias = bf2f(qrelL[q * 132 + idc]);
          const float e = E[qt][kt][jj] + bias;
          const bool bad = (dpos > 127) || (dpos < -127) ||
                           ((unsigned)kglob >= (unsigned)S_LEN);
          E[qt][kt][jj] = bad ? -1e30f : e;
        }
      }

    // ---- online softmax (row spread over 16-lane group) ----
#pragma unroll
    for (int qt = 0; qt < 2; ++qt)
#pragma unroll
      for (int jj = 0; jj < 4; ++jj) {
        float mx = fmaxf(fmaxf(E[qt][0][jj], E[qt][1][jj]),
                         fmaxf(E[qt][2][jj], E[qt][3][jj]));
        mx = fmaxf(mx, __shfl_xor(mx, 1));
        mx = fmaxf(mx, __shfl_xor(mx, 2));
        mx = fmaxf(mx, __shfl_xor(mx, 4));
        mx = fmaxf(mx, __shfl_xor(mx, 8));
        const float nm = fmaxf(m_r[qt][jj], mx);
        const float sc = __expf(m_r[qt][jj] - nm);
        m_r[qt][jj] = nm;
        l_r[qt][jj] *= sc;
#pragma unroll
        for (int dt = 0; dt < 4; ++dt) Oa[qt][dt][jj] *= sc;
        float ps = 0.f;
#pragma unroll
        for (int kt = 0; kt < 4; ++kt) {
          const float p = __expf(E[qt][kt][jj] - nm);
          ps += p;
          Pl[w][(qt * 16 + g * 4 + jj) * 72 + lc + 16 * kt] = f2bf(p);
        }
        ps += __shfl_xor(ps, 1);
        ps += __shfl_xor(ps, 2);
        ps += __shfl_xor(ps, 4);
        ps += __shfl_xor(ps, 8);
        l_r[qt][jj] += ps;
      }
    __syncthreads();  // cross-lane LDS hazard: P writes -> P fragment reads

    // ---- PV: O[q][d] += P[q][k] V[k][d] ----
#pragma unroll
    for (int c = 0; c < 2; ++c) {
      bf16x8 pf[2];
#pragma unroll
      for (int qt = 0; qt < 2; ++qt)
        pf[qt] = *(const bf16x8*)&Pl[w][(lc + 16 * qt) * 72 + g * 8 + 32 * c];
#pragma unroll
      for (int dt = 0; dt < 4; ++dt) {
        const bf16x8 vf =
            *(const bf16x8*)&Vt[(lc + 16 * dt) * 72 + g * 8 + 32 * c];
#pragma unroll
        for (int qt = 0; qt < 2; ++qt)
          Oa[qt][dt] = __builtin_amdgcn_mfma_f32_16x16x32_bf16(pf[qt], vf,
                                                               Oa[qt][dt], 0, 0, 0);
      }
    }
    __syncthreads();  // protect Ks/Vt/Pl before next staging
  }

  // ---- epilogue: normalize, write bf16 (b,h,s,d) ----
  u16* prow = pre + (bh * S_LEN + (size_t)n * 128 + w * 32) * HD;
#pragma unroll
  for (int qt = 0; qt < 2; ++qt)
#pragma unroll
    for (int jj = 0; jj < 4; ++jj) {
      const float inv = 1.f / l_r[qt][jj];
      const int row = qt * 16 + g * 4 + jj;
#pragma unroll
      for (int dt = 0; dt < 4; ++dt)
        prow[row * HD + lc + 16 * dt] = f2bf(Oa[qt][dt][jj] * inv);
    }
}

// ---------------------------------------------------------------------------
extern "C" void kernel_launch(void* const* d_in, const int* in_sizes, int n_in,
                              void* d_out, int out_size, void* d_ws,
                              size_t ws_size, hipStream_t stream) {
  const float* Q = (const float*)d_in[0];
  const float* K = (const float*)d_in[1];
  const float* V = (const float*)d_in[2];
  const float* Wq = (const float*)d_in[4];
  const float* Wk = (const float*)d_in[5];
  const float* Wv = (const float*)d_in[6];
  const float* Wo = (const float*)d_in[7];
  const float* rel = (const float*)d_in[8];
  float* out = (float*)d_out;

  const size_t NE = 4194304;  // 2*8*4096*64
  u16* ws16 = (u16*)d_ws;
  u16* Qb = ws16;
  u16* Kb = Qb + NE;
  u16* Vb = Kb + NE;
  u16* qb = Vb + NE;
  u16* kb = qb + NE;
  u16* vb = kb + NE;
  u16* WqT = vb + NE;
  u16* WkT = WqT + 262144;
  u16* WvT = WkT + 262144;
  u16* WoT = WvT + 262144;
  u16* relb = WoT + 262144;  // 8*144*64 = 73728
  u16* pre = Qb;             // Qb dead after proj GEMM

  conv_big<<<dim3(4096, 3), 256, 0, stream>>>(Q, K, V, Qb, Kb, Vb);
  conv_w<<<dim3(256, 4), 256, 0, stream>>>(Wq, Wk, Wv, Wo, WqT, WkT, WvT, WoT);
  conv_rel<<<dim3(129), 128, 0, stream>>>(rel, relb);
  gemm_bf16<1><<<dim3(64, 4, 3), 256, 0, stream>>>(Qb, Kb, Vb, WqT, WkT, WvT,
                                                   qb, kb, vb, nullptr);
  attn_mfma<<<dim3(NB, NH, 2), 256, 0, stream>>>(qb, kb, vb, relb, pre);
  gemm_bf16<2><<<dim3(64, 4, 1), 256, 0, stream>>>(
      pre, nullptr, nullptr, WoT, nullptr, nullptr, nullptr, nullptr, nullptr,
      out);
}

// Round 4
// 185.028 us; speedup vs baseline: 2.8097x; 1.0222x over previous
//
#include <hip/hip_runtime.h>
#include <hip/hip_bf16.h>

typedef unsigned short u16;
typedef __bf16 bf16_t;
typedef bf16_t bf16x8 __attribute__((ext_vector_type(8)));
typedef float f32x4 __attribute__((ext_vector_type(4)));
typedef u16 u16x4 __attribute__((ext_vector_type(4)));
typedef u16 u16x8 __attribute__((ext_vector_type(8)));

#define S_LEN 4096
#define NH 8
#define HD 64
#define DM 512
#define NB 32

__device__ __forceinline__ u16 f2bf(float f) {
  unsigned int u = __builtin_bit_cast(unsigned int, f);
  u = (u + 0x7fff + ((u >> 16) & 1)) >> 16;  // RNE
  return (u16)u;
}
__device__ __forceinline__ float bf2f(u16 h) {
  unsigned int u = ((unsigned int)h) << 16;
  return __builtin_bit_cast(float, u);
}

#define GLDS16(gaddr, laddr)                                                  \
  __builtin_amdgcn_global_load_lds(                                           \
      (const __attribute__((address_space(1))) unsigned int*)(gaddr),         \
      (__attribute__((address_space(3))) unsigned int*)(laddr), 16, 0, 0)

// ---------------------------------------------------------------------------
// fp32 -> bf16 flat convert for Q,K,V. grid (4096,3) x 256.
// ---------------------------------------------------------------------------
__global__ __launch_bounds__(256) void conv_big(
    const float* __restrict__ Q, const float* __restrict__ K,
    const float* __restrict__ V, u16* __restrict__ Qb, u16* __restrict__ Kb,
    u16* __restrict__ Vb) {
  const int z = blockIdx.y;
  const float* src = z == 0 ? Q : (z == 1 ? K : V);
  u16* dst = z == 0 ? Qb : (z == 1 ? Kb : Vb);
  const size_t idx = ((size_t)blockIdx.x * 256 + threadIdx.x) * 4;
  const float4 v = *(const float4*)(src + idx);
  u16x4 o;
  o[0] = f2bf(v.x); o[1] = f2bf(v.y); o[2] = f2bf(v.z); o[3] = f2bf(v.w);
  *(u16x4*)(dst + idx) = o;
}

// ---------------------------------------------------------------------------
// Weights: fp32 [K][N] -> bf16 transposed [N][K]; Wq scaled 1/8 (folds
// 1/sqrt(hd) into q so energy AND rel-bias are both scaled); Wo row-permuted
// (wrow = (k&63)*8 + (k>>6)) to fold transpose(0,2,3,1). grid (256,4) x 256.
// ---------------------------------------------------------------------------
__global__ __launch_bounds__(256) void conv_w(
    const float* __restrict__ Wq, const float* __restrict__ Wk,
    const float* __restrict__ Wv, const float* __restrict__ Wo,
    u16* __restrict__ WqT, u16* __restrict__ WkT, u16* __restrict__ WvT,
    u16* __restrict__ WoT) {
  const int z = blockIdx.y;
  const float* src = z == 0 ? Wq : (z == 1 ? Wk : (z == 2 ? Wv : Wo));
  u16* dst = z == 0 ? WqT : (z == 1 ? WkT : (z == 2 ? WvT : WoT));
  const float scl = (z == 0) ? 0.125f : 1.f;
  const int idx4 = blockIdx.x * 256 + threadIdx.x;
  const int nrow = idx4 >> 7;
  const int kbase = (idx4 & 127) * 4;
  u16x4 o;
#pragma unroll
  for (int j = 0; j < 4; ++j) {
    const int k = kbase + j;
    const int srow = (z == 3) ? ((k & 63) * 8 + (k >> 6)) : k;
    o[j] = f2bf(src[srow * DM + nrow] * scl);
  }
  *(u16x4*)(dst + nrow * DM + kbase) = o;
}

// ---------------------------------------------------------------------------
// rel_emb fp32 [8][129][64] -> bf16 [8][144][64] (row-padded; pad rows never
// read: idc <= 128). grid 129 x 128.
// ---------------------------------------------------------------------------
__global__ __launch_bounds__(128) void conv_rel(const float* __restrict__ rel,
                                                u16* __restrict__ relb) {
  const int e = (blockIdx.x * 128 + threadIdx.x) * 4;
  const int h = e / (129 * 64);
  const int rem = e - h * (129 * 64);
  const float4 v = *(const float4*)(rel + e);
  u16x4 o;
  o[0] = f2bf(v.x); o[1] = f2bf(v.y); o[2] = f2bf(v.z); o[3] = f2bf(v.w);
  *(u16x4*)(relb + (size_t)h * (144 * 64) + rem) = o;
}

// ---------------------------------------------------------------------------
// bf16 MFMA GEMM, 128x128 tile, BK=32, 4 waves, double-buffered LDS with
// prefetch-before-compute (2-phase: one barrier per K-step). MFMA operands
// SWAPPED (D = C^T layout) so each thread holds 4 consecutive N-dim values
// -> vectorized epilogue (u16x4 / float4 stores).
// MODE 1: A row-major; C scattered bf16 to (b,h,s,d); z picks Q/K/V.
// MODE 2: A = attn-out in (b,h,s,d), k = h*64+d addressing; C fp32 row-major.
// ---------------------------------------------------------------------------
template <int MODE>
__global__ __launch_bounds__(256, 2) void gemm_bf16(
    const u16* __restrict__ A0, const u16* __restrict__ A1,
    const u16* __restrict__ A2, const u16* __restrict__ B0,
    const u16* __restrict__ B1, const u16* __restrict__ B2,
    u16* __restrict__ C0, u16* __restrict__ C1, u16* __restrict__ C2,
    float* __restrict__ Cf) {
  __shared__ u16 As[2][128 * 32];
  __shared__ u16 Bs[2][128 * 32];

  const int z = blockIdx.z;
  const u16* A = (MODE == 1) ? (z == 0 ? A0 : (z == 1 ? A1 : A2)) : A0;
  const u16* Bt = (MODE == 1) ? (z == 0 ? B0 : (z == 1 ? B1 : B2)) : B0;
  u16* Cb = (MODE == 1) ? (z == 0 ? C0 : (z == 1 ? C1 : C2)) : (u16*)0;

  const int tid = threadIdx.x;
  const int lane = tid & 63;
  const int w = tid >> 6;
  const int bm = blockIdx.x * 128;
  const int bn = blockIdx.y * 128;

  const int srow = lane >> 2;       // 0..15 within chunk
  const int scol = (lane & 3) * 8;  // k offset 0,8,16,24

  f32x4 acc[4][4];
#pragma unroll
  for (int m = 0; m < 4; ++m)
#pragma unroll
    for (int nf = 0; nf < 4; ++nf) acc[m][nf] = f32x4{0.f, 0.f, 0.f, 0.f};

  const int wr = w >> 1, wc = w & 1;
  const int lrow = lane & 15;
  const int lk = (lane >> 4) * 8;

  auto stage = [&](int buf, int k0) {
#pragma unroll
    for (int t = 0; t < 2; ++t) {
      const int c = t * 4 + w;       // chunk 0..7 -> rows [c*16, c*16+16)
      const int ar = c * 16 + srow;  // tile row
      long gidx;
      if (MODE == 2) {
        const int r = bm + ar;
        const int b = r >> 12, s = r & 4095;
        const int k = k0 + scol;
        gidx = ((long)((b * 8 + (k >> 6)) * 4096 + s)) * 64 + (k & 63);
      } else {
        gidx = (long)(bm + ar) * DM + k0 + scol;
      }
      GLDS16(A + gidx, &As[buf][c * 512]);
      const long bidx = (long)(bn + ar) * DM + k0 + scol;
      GLDS16(Bt + bidx, &Bs[buf][c * 512]);
    }
  };

  stage(0, 0);
  __syncthreads();  // implicit vmcnt(0) drains prologue stage

  for (int t = 0; t < 16; ++t) {
    const int cur = t & 1;
    if (t < 15) stage(cur ^ 1, (t + 1) * 32);  // prefetch next tile

    bf16x8 af[4], bfr[4];
#pragma unroll
    for (int m = 0; m < 4; ++m)
      af[m] = *(const bf16x8*)&As[cur][(wr * 64 + m * 16 + lrow) * 32 + lk];
#pragma unroll
    for (int nf = 0; nf < 4; ++nf)
      bfr[nf] = *(const bf16x8*)&Bs[cur][(wc * 64 + nf * 16 + lrow) * 32 + lk];
#pragma unroll
    for (int m = 0; m < 4; ++m)
#pragma unroll
      for (int nf = 0; nf < 4; ++nf)
        acc[m][nf] = __builtin_amdgcn_mfma_f32_16x16x32_bf16(
            bfr[nf], af[m], acc[m][nf], 0, 0, 0);  // swapped: D = C^T layout
    __syncthreads();  // drains prefetch (vmcnt0) + protects cur for overwrite
  }

  // epilogue: D row=(lane>>4)*4+j -> N-dim, col=lane&15 -> M-dim
  const int lr4 = (lane >> 4) * 4;
  const int lc = lane & 15;
#pragma unroll
  for (int m = 0; m < 4; ++m) {
    const int r = bm + wr * 64 + m * 16 + lc;  // output row (s-dim)
    const int bi = r >> 12, s = r & 4095;
#pragma unroll
    for (int nf = 0; nf < 4; ++nf) {
      const int cg = bn + wc * 64 + nf * 16 + lr4;  // output col (d-dim), %4==0
      if (MODE == 1) {
        u16x4 o;
#pragma unroll
        for (int j = 0; j < 4; ++j) o[j] = f2bf(acc[m][nf][j]);
        *(u16x4*)&Cb[((long)((bi * 8 + (cg >> 6)) * 4096 + s)) * 64 +
                     (cg & 63)] = o;
      } else {
        float4 o;
        o.x = acc[m][nf][0]; o.y = acc[m][nf][1];
        o.z = acc[m][nf][2]; o.w = acc[m][nf][3];
        *(float4*)&Cf[(long)r * DM + cg] = o;
      }
    }
  }
}

// ---------------------------------------------------------------------------
// MFMA local attention. grid (32,8,2) x 256 (4 waves, 32 q each).
// Per kv-tile (64 keys): QK^T 16 MFMA, bias gather from LDS qrel table,
// wave-parallel online softmax with T13 defer-rescale (THR=8), P via per-wave
// LDS, PV 16 MFMA. K row-major [64][72]; V transposed [64d][72k].
// kglob bounds never trigger given t0/t1 trimming -> only |dpos|<=127 mask.
// ---------------------------------------------------------------------------
__global__ __launch_bounds__(256, 2) void attn_mfma(
    const u16* __restrict__ qg, const u16* __restrict__ kgl,
    const u16* __restrict__ vgl, const u16* __restrict__ relb,
    u16* __restrict__ pre) {
  const int n = blockIdx.x, hh = blockIdx.y, b = blockIdx.z;
  const int tid = threadIdx.x;
  const int lane = tid & 63, w = tid >> 6;
  const int g = lane >> 4, lc = lane & 15;

  __shared__ u16 Ks[64 * 72];
  __shared__ u16 Vt[64 * 72];
  __shared__ u16 Pl[4][32 * 72];
  __shared__ u16 qrelL[128 * 132];

  const size_t bh = (size_t)(b * NH + hh);

  // ---- Q fragments ----
  const u16* qbase = qg + (bh * S_LEN + (size_t)n * 128 + w * 32) * HD;
  bf16x8 qf[2][2];
#pragma unroll
  for (int qt = 0; qt < 2; ++qt)
#pragma unroll
    for (int dc = 0; dc < 2; ++dc)
      qf[qt][dc] =
          *(const bf16x8*)(qbase + (lc + 16 * qt) * HD + g * 8 + 32 * dc);

  // ---- qrel table via MFMA ----
  const u16* rh = relb + (size_t)hh * (144 * 64);
#pragma unroll
  for (int rt = 0; rt < 9; ++rt) {
    f32x4 acc[2] = {{0.f, 0.f, 0.f, 0.f}, {0.f, 0.f, 0.f, 0.f}};
#pragma unroll
    for (int dc = 0; dc < 2; ++dc) {
      const bf16x8 rf =
          *(const bf16x8*)(rh + (lc + 16 * rt) * 64 + g * 8 + 32 * dc);
#pragma unroll
      for (int qt = 0; qt < 2; ++qt)
        acc[qt] = __builtin_amdgcn_mfma_f32_16x16x32_bf16(qf[qt][dc], rf,
                                                          acc[qt], 0, 0, 0);
    }
#pragma unroll
    for (int qt = 0; qt < 2; ++qt)
#pragma unroll
      for (int jj = 0; jj < 4; ++jj)
        qrelL[(w * 32 + qt * 16 + g * 4 + jj) * 132 + lc + 16 * rt] =
            f2bf(acc[qt][jj]);
  }

  float m_r[2][4], l_r[2][4];
  f32x4 Oa[2][4];
#pragma unroll
  for (int qt = 0; qt < 2; ++qt)
#pragma unroll
    for (int jj = 0; jj < 4; ++jj) {
      m_r[qt][jj] = -1e30f;
      l_r[qt][jj] = 0.f;
    }
#pragma unroll
  for (int qt = 0; qt < 2; ++qt)
#pragma unroll
    for (int dt = 0; dt < 4; ++dt) Oa[qt][dt] = f32x4{0.f, 0.f, 0.f, 0.f};

  const u16* kbase = kgl + bh * S_LEN * HD;
  const u16* vbase = vgl + bh * S_LEN * HD;
  const int sk = tid & 63;
  const int sd = (tid >> 6) * 16;

  const int t0 = (n == 0) ? 2 : 0;
  const int t1 = (n == NB - 1) ? 4 : 6;

  for (int t = t0; t < t1; ++t) {
    // ---- stage K row-major + V transposed ----
    {
      const int kglob = n * 128 - 128 + t * 64 + sk;
      const int kc = min(max(kglob, 0), S_LEN - 1);
      const u16* krow = kbase + (size_t)kc * HD + sd;
      const u16* vrow = vbase + (size_t)kc * HD + sd;
      const u16x8 ka = *(const u16x8*)krow;
      const u16x8 kb2 = *(const u16x8*)(krow + 8);
      const u16x8 va = *(const u16x8*)vrow;
      const u16x8 vb2 = *(const u16x8*)(vrow + 8);
      *(u16x8*)&Ks[sk * 72 + sd] = ka;
      *(u16x8*)&Ks[sk * 72 + sd + 8] = kb2;
#pragma unroll
      for (int e = 0; e < 8; ++e) {
        Vt[(sd + e) * 72 + sk] = va[e];
        Vt[(sd + 8 + e) * 72 + sk] = vb2[e];
      }
    }
    __syncthreads();

    // ---- QK^T ----
    f32x4 E[2][4];
#pragma unroll
    for (int qt = 0; qt < 2; ++qt)
#pragma unroll
      for (int kt = 0; kt < 4; ++kt) E[qt][kt] = f32x4{0.f, 0.f, 0.f, 0.f};
#pragma unroll
    for (int kt = 0; kt < 4; ++kt)
#pragma unroll
      for (int dc = 0; dc < 2; ++dc) {
        const bf16x8 kf =
            *(const bf16x8*)&Ks[(lc + 16 * kt) * 72 + g * 8 + 32 * dc];
#pragma unroll
        for (int qt = 0; qt < 2; ++qt)
          E[qt][kt] = __builtin_amdgcn_mfma_f32_16x16x32_bf16(
              qf[qt][dc], kf, E[qt][kt], 0, 0, 0);
      }

    // ---- bias + mask ----
#pragma unroll
    for (int qt = 0; qt < 2; ++qt)
#pragma unroll
      for (int jj = 0; jj < 4; ++jj) {
        const int q = w * 32 + qt * 16 + g * 4 + jj;
#pragma unroll
        for (int kt = 0; kt < 4; ++kt) {
          const int j = t * 64 + kt * 16 + lc;
          const int dpos = j - 128 - q;
          const int idc = min(max(dpos, -64), 64) + 64;
          const float bias = bf2f(qrelL[q * 132 + idc]);
          const float e = E[qt][kt][jj] + bias;
          const bool bad = ((unsigned)(dpos + 127) > 254u);  // |dpos|>127
          E[qt][kt][jj] = bad ? -1e30f : e;
        }
      }

    // ---- online softmax with defer-rescale (T13, THR=8) ----
    float mxv[2][4];
    bool loc = true;
#pragma unroll
    for (int qt = 0; qt < 2; ++qt)
#pragma unroll
      for (int jj = 0; jj < 4; ++jj) {
        float mx = fmaxf(fmaxf(E[qt][0][jj], E[qt][1][jj]),
                         fmaxf(E[qt][2][jj], E[qt][3][jj]));
        mx = fmaxf(mx, __shfl_xor(mx, 1));
        mx = fmaxf(mx, __shfl_xor(mx, 2));
        mx = fmaxf(mx, __shfl_xor(mx, 4));
        mx = fmaxf(mx, __shfl_xor(mx, 8));
        mxv[qt][jj] = mx;
        loc = loc && (mx <= m_r[qt][jj] + 8.f);
      }
    if (!__all(loc)) {
#pragma unroll
      for (int qt = 0; qt < 2; ++qt)
#pragma unroll
        for (int jj = 0; jj < 4; ++jj) {
          const float nm = fmaxf(m_r[qt][jj], mxv[qt][jj]);
          const float sc = __expf(m_r[qt][jj] - nm);
          m_r[qt][jj] = nm;
          l_r[qt][jj] *= sc;
#pragma unroll
          for (int dt = 0; dt < 4; ++dt) Oa[qt][dt][jj] *= sc;
        }
    }
#pragma unroll
    for (int qt = 0; qt < 2; ++qt)
#pragma unroll
      for (int jj = 0; jj < 4; ++jj) {
        float ps = 0.f;
#pragma unroll
        for (int kt = 0; kt < 4; ++kt) {
          const float p = __expf(E[qt][kt][jj] - m_r[qt][jj]);
          ps += p;
          Pl[w][(qt * 16 + g * 4 + jj) * 72 + lc + 16 * kt] = f2bf(p);
        }
        ps += __shfl_xor(ps, 1);
        ps += __shfl_xor(ps, 2);
        ps += __shfl_xor(ps, 4);
        ps += __shfl_xor(ps, 8);
        l_r[qt][jj] += ps;
      }
    __syncthreads();  // P writes -> P fragment reads

    // ---- PV ----
#pragma unroll
    for (int c = 0; c < 2; ++c) {
      bf16x8 pf[2];
#pragma unroll
      for (int qt = 0; qt < 2; ++qt)
        pf[qt] = *(const bf16x8*)&Pl[w][(lc + 16 * qt) * 72 + g * 8 + 32 * c];
#pragma unroll
      for (int dt = 0; dt < 4; ++dt) {
        const bf16x8 vf =
            *(const bf16x8*)&Vt[(lc + 16 * dt) * 72 + g * 8 + 32 * c];
#pragma unroll
        for (int qt = 0; qt < 2; ++qt)
          Oa[qt][dt] = __builtin_amdgcn_mfma_f32_16x16x32_bf16(
              pf[qt], vf, Oa[qt][dt], 0, 0, 0);
      }
    }
    __syncthreads();  // protect Ks/Vt/Pl before next staging
  }

  // ---- epilogue ----
  u16* prow = pre + (bh * S_LEN + (size_t)n * 128 + w * 32) * HD;
#pragma unroll
  for (int qt = 0; qt < 2; ++qt)
#pragma unroll
    for (int jj = 0; jj < 4; ++jj) {
      const float inv = 1.f / l_r[qt][jj];
      const int row = qt * 16 + g * 4 + jj;
#pragma unroll
      for (int dt = 0; dt < 4; ++dt)
        prow[row * HD + lc + 16 * dt] = f2bf(Oa[qt][dt][jj] * inv);
    }
}

// ---------------------------------------------------------------------------
extern "C" void kernel_launch(void* const* d_in, const int* in_sizes, int n_in,
                              void* d_out, int out_size, void* d_ws,
                              size_t ws_size, hipStream_t stream) {
  const float* Q = (const float*)d_in[0];
  const float* K = (const float*)d_in[1];
  const float* V = (const float*)d_in[2];
  const float* Wq = (const float*)d_in[4];
  const float* Wk = (const float*)d_in[5];
  const float* Wv = (const float*)d_in[6];
  const float* Wo = (const float*)d_in[7];
  const float* rel = (const float*)d_in[8];
  float* out = (float*)d_out;

  const size_t NE = 4194304;  // 2*8*4096*64
  u16* ws16 = (u16*)d_ws;
  u16* Qb = ws16;
  u16* Kb = Qb + NE;
  u16* Vb = Kb + NE;
  u16* qb = Vb + NE;
  u16* kb = qb + NE;
  u16* vb = kb + NE;
  u16* WqT = vb + NE;
  u16* WkT = WqT + 262144;
  u16* WvT = WkT + 262144;
  u16* WoT = WvT + 262144;
  u16* relb = WoT + 262144;  // 8*144*64
  u16* pre = Qb;             // Qb dead after proj GEMM

  conv_big<<<dim3(4096, 3), 256, 0, stream>>>(Q, K, V, Qb, Kb, Vb);
  conv_w<<<dim3(256, 4), 256, 0, stream>>>(Wq, Wk, Wv, Wo, WqT, WkT, WvT, WoT);
  conv_rel<<<dim3(129), 128, 0, stream>>>(rel, relb);
  gemm_bf16<1><<<dim3(64, 4, 3), 256, 0, stream>>>(Qb, Kb, Vb, WqT, WkT, WvT,
                                                   qb, kb, vb, nullptr);
  attn_mfma<<<dim3(NB, NH, 2), 256, 0, stream>>>(qb, kb, vb, relb, pre);
  gemm_bf16<2><<<dim3(64, 4, 1), 256, 0, stream>>>(
      pre, nullptr, nullptr, WoT, nullptr, nullptr, nullptr, nullptr, nullptr,
      out);
}